// Round 7
// baseline (95045.410 us; speedup 1.0000x reference)
//
#include <hip/hip_runtime.h>

typedef unsigned int u32;
typedef unsigned short u16;
typedef _Float16 f16;
typedef _Float16 f16x2 __attribute__((ext_vector_type(2)));

#define T_SEQ 32768

// ---------------- ws layout (bytes) ----------------
static const size_t OFF_DT   = 0;         // u32 dtype flag (1 = f32 inputs)
static const size_t OFF_FLG  = 1024;      // u32[128] (legacy, kept zeroed)
static const size_t OFF_MAP  = 4096;      // int [T]
static const size_t OFF_H1G  = 135168;    // f16 [1024][512]
static const size_t OFF_BIAS = 1183744;   // f32 [4][1024]
static const size_t OFF_FCW  = 1200128;   // f32 [512*64]
static const size_t OFF_WQ8  = 1331200;   // u32 [4][1024][64] int8 W_hh (1 MB)
static const size_t OFF_WIH0 = 3428352;   // u32 [2][1024][32]
static const size_t OFF_WIH1 = 3690496;   // u32 [2][1024][256]
static const size_t OFF_XQ   = 5787648;   // u32 [T][32]
static const size_t OFF_H0   = 9981952;   // f16 [T][512]
static const size_t OFF_XG   = 43536384;  // f16 [ndir][T][1024], LAST (adaptive)
static const size_t XG_DIR   = (size_t)T_SEQ * 1024 * 2;  // 67108864 bytes
static const size_t NEED_PAR = OFF_XG + 2 * XG_DIR;       // 177754112

// ---------------- helpers ----------------
__device__ __forceinline__ float bf2f(u16 u) {
  union { u32 i; float f; } v; v.i = ((u32)u) << 16; return v.f;
}
__device__ __forceinline__ u16 f2bf(float f) {
  union { float f; u32 i; } v; v.f = f;
  u32 u = v.i;
  return (u16)((u + 0x7fffu + ((u >> 16) & 1u)) >> 16);
}
__device__ __forceinline__ u32 packf2(float a, float b) {
  f16x2 p; p.x = (f16)a; p.y = (f16)b;
  return __builtin_bit_cast(u32, p);
}
__device__ __forceinline__ u32 bf2f2(u32 v) {  // two bf16 -> two f16
  union { u32 i; float f; } lo, hi;
  lo.i = v << 16; hi.i = v & 0xffff0000u;
  return packf2(lo.f, hi.f);
}
__device__ __forceinline__ float ldf(const void* p, size_t i, u32 isf) {
  return isf ? ((const float*)p)[i] : bf2f(((const u16*)p)[i]);
}
__device__ __forceinline__ float fdot2f(f16x2 a, f16x2 b, float c) {
#if __has_builtin(__builtin_amdgcn_fdot2)
  return __builtin_amdgcn_fdot2(a, b, c, false);
#else
  return c + (float)a.x * (float)b.x + (float)a.y * (float)b.y;
#endif
}
__device__ __forceinline__ float fdotu(u32 a, u32 b, float c) {
  return fdot2f(__builtin_bit_cast(f16x2, a), __builtin_bit_cast(f16x2, b), c);
}
__device__ __forceinline__ int sdot4(u32 a, u32 b, int c) {
#if __has_builtin(__builtin_amdgcn_sdot4)
  return __builtin_amdgcn_sdot4((int)a, (int)b, c, false);
#else
  int r = c;
#pragma unroll
  for (int j = 0; j < 4; ++j)
    r += (int)(signed char)(a >> (8 * j)) * (int)(signed char)(b >> (8 * j));
  return r;
#endif
}
__device__ __forceinline__ float sigf(float x) {
  return __builtin_amdgcn_rcpf(1.0f + __builtin_amdgcn_exp2f(-1.4426950408889634f * x));
}
__device__ __forceinline__ float tanhf_fast(float x) {
  return 1.0f - 2.0f * __builtin_amdgcn_rcpf(1.0f + __builtin_amdgcn_exp2f(2.8853900817779268f * x));
}

// ---------------- dtype detection ----------------
__global__ void k_detect(const u16* __restrict__ probe, u32* __restrict__ dt) {
  __shared__ int cnt;
  if (threadIdx.x == 0) cnt = 0;
  __syncthreads();
  int bad = 0;
  for (int i = threadIdx.x; i < 8192; i += 256) {
    float v = bf2f(probe[i]);
    if (!(v * v <= 16.0f)) bad++;
  }
  atomicAdd(&cnt, bad);
  __syncthreads();
  if (threadIdx.x == 0) *dt = (cnt > 64) ? 1u : 0u;
}

// ---------------- conversions ----------------
__global__ void k_conv_pairs(const void* __restrict__ src, u32* __restrict__ dst,
                             int np, const u32* __restrict__ dtp) {
  u32 isf = *dtp;
  int i = blockIdx.x * 256 + threadIdx.x;
  if (i >= np) return;
  if (isf) {
    const float* s = (const float*)src;
    dst[i] = packf2(s[2 * i], s[2 * i + 1]);
  } else {
    dst[i] = bf2f2(((const u32*)src)[i]);
  }
}

// int8-quantize one W_hh matrix [1024][256] -> u32 [1024][64], scale 2048
__global__ void k_quant(const void* __restrict__ src, u32* __restrict__ dst,
                        const u32* __restrict__ dtp) {
  u32 isf = *dtp;
  int i = blockIdx.x * 256 + threadIdx.x;  // 65536
  int row = i >> 6, c = i & 63;
  u32 out = 0;
#pragma unroll
  for (int j = 0; j < 4; ++j) {
    float w = ldf(src, (size_t)row * 256 + 4 * c + j, isf);
    int q = (int)rintf(w * 2048.0f);
    q = q > 127 ? 127 : (q < -127 ? -127 : q);
    out |= ((u32)(q & 0xff)) << (8 * j);
  }
  dst[i] = out;
}

__global__ void k_conv_misc(const void* bi0f, const void* bh0f, const void* bi0b, const void* bh0b,
                            const void* bi1f, const void* bh1f, const void* bi1b, const void* bh1b,
                            const void* fcb, float* __restrict__ bias, float* __restrict__ fcw,
                            u32* __restrict__ flags, int* __restrict__ map,
                            const u32* __restrict__ dtp) {
  u32 isf = *dtp;
  int i = blockIdx.x * 256 + threadIdx.x;
  if (i < 4096) {
    int ld = i >> 10, r = i & 1023;
    const void* bi; const void* bh;
    if (ld == 0)      { bi = bi0f; bh = bh0f; }
    else if (ld == 1) { bi = bi0b; bh = bh0b; }
    else if (ld == 2) { bi = bi1f; bh = bh1f; }
    else              { bi = bi1b; bh = bh1b; }
    bias[i] = ldf(bi, r, isf) + ldf(bh, r, isf);
  } else if (i < 36864) {
    fcw[i - 4096] = ldf(fcb, i - 4096, isf);
  } else if (i < 36992) {
    flags[i - 36864] = 0;
  } else if (i < 69760) {
    map[i - 36992] = -1;
  }
}

__global__ void k_conv_x(const void* __restrict__ Y, const void* __restrict__ dT,
                         u32* __restrict__ xq, const u32* __restrict__ dtp) {
  u32 isf = *dtp;
  int i = blockIdx.x * 256 + threadIdx.x;  // T*32
  if (i >= T_SEQ * 32) return;
  int t = i >> 5, m = i & 31, k2 = 2 * m;
  float a = ldf(Y, (size_t)t * 63 + k2, isf);
  float b = (k2 + 1 < 63) ? ldf(Y, (size_t)t * 63 + k2 + 1, isf) : ldf(dT, t, isf);
  xq[i] = packf2(a, b);
}

__global__ void k_map_set(const int* __restrict__ idx, int* __restrict__ map) {
  int i = blockIdx.x * 256 + threadIdx.x;
  if (i < 1024) map[idx[i]] = i;
}

// ---------------- input-projection GEMM ----------------
__global__ __launch_bounds__(256) void k_gemm(
    const u32* __restrict__ Aq, const u32* __restrict__ Wc,
    const float* __restrict__ bias, f16* __restrict__ xg_slot, int Kp) {
  int t0 = blockIdx.x << 6, r0 = blockIdx.y << 6;
  int tid = threadIdx.x, tx = tid & 15, ty = tid >> 4;
  __shared__ u32 As[64][33];
  __shared__ u32 Bs[64][33];
  float acc[4][4] = {};
  for (int kp0 = 0; kp0 < Kp; kp0 += 32) {
#pragma unroll
    for (int i = 0; i < 8; ++i) {
      int idx = tid + (i << 8);
      int row = idx >> 5, kp = idx & 31, kpg = kp0 + kp;
      As[row][kp] = Aq[(size_t)(t0 + row) * Kp + kpg];
      Bs[row][kp] = Wc[(size_t)(r0 + row) * Kp + kpg];
    }
    __syncthreads();
#pragma unroll 4
    for (int kk = 0; kk < 32; ++kk) {
      u32 av[4], bv[4];
#pragma unroll
      for (int i = 0; i < 4; ++i) av[i] = As[ty * 4 + i][kk];
#pragma unroll
      for (int i = 0; i < 4; ++i) bv[i] = Bs[tx * 4 + i][kk];
#pragma unroll
      for (int i = 0; i < 4; ++i)
#pragma unroll
        for (int j = 0; j < 4; ++j)
          acc[i][j] = fdotu(av[i], bv[j], acc[i][j]);
    }
    __syncthreads();
  }
#pragma unroll
  for (int i = 0; i < 4; ++i) {
    int t = t0 + ty * 4 + i;
#pragma unroll
    for (int j = 0; j < 4; ++j) {
      int r = r0 + tx * 4 + j;
      xg_slot[(size_t)t * 1024 + r] = (f16)(acc[i][j] + bias[r]);
    }
  }
}

// ---------------- recurrence v3: 256 threads, all 4 gates per thread --------
// Thread tid owns hidden unit tid: gate rows {tid, 256+tid, 512+tid, 768+tid},
// each 64 u32 of int8 weights -> 256 u32 ALL in VGPRs. launch_bounds(256,1)
// legitimizes ~290 VGPRs (1 wave/SIMD budget = 512) so the allocator has no
// occupancy tier to chase by spilling (R4-R6 lesson: bounds only set floors).
// No gate exchange needed -> single barrier/step with double-buffered hpk.
__global__ __launch_bounds__(256, 1) void k_recur3(
    const f16* __restrict__ xg, const u32* __restrict__ wq,
    f16* __restrict__ h_full, f16* __restrict__ h1g,
    const int* __restrict__ map, int dir0) {
  const int dir = dir0 + blockIdx.x;
  const int tid = threadIdx.x;
  const u32* wqd = wq + ((size_t)dir << 16);  // [1024][64]

  __shared__ __align__(16) u32 hpk[2][64];    // h as i8[256], double-buffered

  u32 w0[64], w1[64], w2[64], w3[64];
  {
    const uint4* p0 = (const uint4*)(wqd + ((size_t)tid) * 64);
    const uint4* p1 = (const uint4*)(wqd + ((size_t)(256 + tid)) * 64);
    const uint4* p2 = (const uint4*)(wqd + ((size_t)(512 + tid)) * 64);
    const uint4* p3 = (const uint4*)(wqd + ((size_t)(768 + tid)) * 64);
#pragma unroll
    for (int i = 0; i < 16; ++i) {
      uint4 v;
      v = p0[i]; w0[4*i] = v.x; w0[4*i+1] = v.y; w0[4*i+2] = v.z; w0[4*i+3] = v.w;
      v = p1[i]; w1[4*i] = v.x; w1[4*i+1] = v.y; w1[4*i+2] = v.z; w1[4*i+3] = v.w;
      v = p2[i]; w2[4*i] = v.x; w2[4*i+1] = v.y; w2[4*i+2] = v.z; w2[4*i+3] = v.w;
      v = p3[i]; w3[4*i] = v.x; w3[4*i+1] = v.y; w3[4*i+2] = v.z; w3[4*i+3] = v.w;
    }
  }
  // Pin weights in VGPRs (blocks rematerialization-from-global).
#pragma unroll
  for (int i = 0; i < 64; ++i) {
    asm volatile("" : "+v"(w0[i]));
    asm volatile("" : "+v"(w1[i]));
    asm volatile("" : "+v"(w2[i]));
    asm volatile("" : "+v"(w3[i]));
  }

  if (tid < 64) { hpk[0][tid] = 0; hpk[1][tid] = 0; }
  float c_state = 0.f;
  const f16* xg_d = xg + ((size_t)blockIdx.x * T_SEQ * 1024);
  const float ksc = 1.0f / (2048.0f * 127.0f);

  int t = dir ? (T_SEQ - 1) : 0;
  float xa0 = (float)xg_d[(size_t)t * 1024 + tid];
  float xa1 = (float)xg_d[(size_t)t * 1024 + 256 + tid];
  float xa2 = (float)xg_d[(size_t)t * 1024 + 512 + tid];
  float xa3 = (float)xg_d[(size_t)t * 1024 + 768 + tid];

  for (int step = 0; step < T_SEQ; ++step) {
    __syncthreads();  // hpk[step&1] written by previous step's tail
    const u32* hp = hpk[step & 1];
    float xi = xa0, xf = xa1, xc = xa2, xo = xa3;
    const int tn = dir ? (T_SEQ - 2 - step) : (step + 1);
    if (step + 1 < T_SEQ) {  // prefetch next xg (wave-uniform branch)
      xa0 = (float)xg_d[(size_t)tn * 1024 + tid];
      xa1 = (float)xg_d[(size_t)tn * 1024 + 256 + tid];
      xa2 = (float)xg_d[(size_t)tn * 1024 + 512 + tid];
      xa3 = (float)xg_d[(size_t)tn * 1024 + 768 + tid];
    }
    int a0 = 0, a1 = 0, a2 = 0, a3 = 0;
#pragma unroll
    for (int c = 0; c < 16; ++c) {
      uint4 hv = *(const uint4*)(hp + 4 * c);
      a0 = sdot4(w0[4*c+0], hv.x, a0);
      a1 = sdot4(w1[4*c+0], hv.x, a1);
      a2 = sdot4(w2[4*c+0], hv.x, a2);
      a3 = sdot4(w3[4*c+0], hv.x, a3);
      a0 = sdot4(w0[4*c+1], hv.y, a0);
      a1 = sdot4(w1[4*c+1], hv.y, a1);
      a2 = sdot4(w2[4*c+1], hv.y, a2);
      a3 = sdot4(w3[4*c+1], hv.y, a3);
      a0 = sdot4(w0[4*c+2], hv.z, a0);
      a1 = sdot4(w1[4*c+2], hv.z, a1);
      a2 = sdot4(w2[4*c+2], hv.z, a2);
      a3 = sdot4(w3[4*c+2], hv.z, a3);
      a0 = sdot4(w0[4*c+3], hv.w, a0);
      a1 = sdot4(w1[4*c+3], hv.w, a1);
      a2 = sdot4(w2[4*c+3], hv.w, a2);
      a3 = sdot4(w3[4*c+3], hv.w, a3);
    }
    float gi = sigf(xi + (float)a0 * ksc);
    float gf = sigf(xf + (float)a1 * ksc);
    float gg = tanhf_fast(xc + (float)a2 * ksc);
    float go = sigf(xo + (float)a3 * ksc);
    c_state = gf * c_state + gi * gg;
    float h = go * tanhf_fast(c_state);
    // i8 pack into the NEXT slot (no second barrier needed: readers of this
    // slot finished before the top-of-step barrier of the current step).
    int q = (int)rintf(h * 127.0f);
    u32 b = (u32)(q & 0xff);
    b |= (u32)(__shfl_xor((int)b, 1) & 0xff) << 8;
    b |= (u32)(__shfl_xor((int)b, 2) & 0xffff) << 16;
    if (!(tid & 3)) hpk[(step + 1) & 1][tid >> 2] = b;
    // f16 pair for downstream consumers
    float hn = __shfl_xor(h, 1);
    if (!(tid & 1)) {
      u32 hv = packf2(h, hn);
      if (h_full)
        ((u32*)(h_full + (size_t)t * 512 + (dir << 8)))[tid >> 1] = hv;
      if (map) {
        int s = map[t];
        if (s >= 0)
          ((u32*)(h1g + (size_t)s * 512 + (dir << 8)))[tid >> 1] = hv;
      }
    }
    t = tn;
  }
}

// ---------------- FC + gather ----------------
__global__ void k_fc(const f16* __restrict__ h1g, const int* __restrict__ map,
                     const int* __restrict__ idx, const float* __restrict__ fcw,
                     void* __restrict__ out, const u32* __restrict__ dtp) {
  u32 isf = *dtp;
  int n = blockIdx.x;
  int cc = threadIdx.x;  // 64
  int slot = map[idx[n]];
  const f16* hp = h1g + (size_t)slot * 512;
  float acc = 0.f;
#pragma unroll 8
  for (int k = 0; k < 512; ++k) acc += (float)hp[k] * fcw[k * 64 + cc];
  int o = (cc < 32) ? (n * 32 + cc) : (32 * 1024 + n * 32 + (cc - 32));
  if (isf) ((float*)out)[o] = acc;
  else     ((u16*)out)[o]   = f2bf(acc);
}

// ---------------- launch ----------------
extern "C" void kernel_launch(void* const* d_in, const int* in_sizes, int n_in,
                              void* d_out, int out_size, void* d_ws, size_t ws_size,
                              hipStream_t stream) {
  const void* Y        = d_in[0];
  const void* dT       = d_in[1];
  const int*  idx      = (const int*)d_in[2];
  const void* w_ih_l0f = d_in[3];
  const void* w_hh_l0f = d_in[4];
  const void* b_ih_l0f = d_in[5];
  const void* b_hh_l0f = d_in[6];
  const void* w_ih_l0b = d_in[7];
  const void* w_hh_l0b = d_in[8];
  const void* b_ih_l0b = d_in[9];
  const void* b_hh_l0b = d_in[10];
  const void* w_ih_l1f = d_in[11];
  const void* w_hh_l1f = d_in[12];
  const void* b_ih_l1f = d_in[13];
  const void* b_hh_l1f = d_in[14];
  const void* w_ih_l1b = d_in[15];
  const void* w_hh_l1b = d_in[16];
  const void* b_ih_l1b = d_in[17];
  const void* b_hh_l1b = d_in[18];
  const void* fcbf     = d_in[19];

  char* ws = (char*)d_ws;
  u32*  dt    = (u32*)(ws + OFF_DT);
  u32*  flags = (u32*)(ws + OFF_FLG);
  int*  map   = (int*)(ws + OFF_MAP);
  f16*  h1g   = (f16*)(ws + OFF_H1G);
  float* bias = (float*)(ws + OFF_BIAS);
  float* fcw  = (float*)(ws + OFF_FCW);
  u32*  wq8   = (u32*)(ws + OFF_WQ8);
  u32*  wih0  = (u32*)(ws + OFF_WIH0);
  u32*  wih1  = (u32*)(ws + OFF_WIH1);
  u32*  xq    = (u32*)(ws + OFF_XQ);
  f16*  h0    = (f16*)(ws + OFF_H0);
  f16*  xg    = (f16*)(ws + OFF_XG);
  f16*  xg1   = xg + XG_DIR / 2;  // f16 elements

  const int par = (ws_size >= NEED_PAR) ? 1 : 0;

  k_detect<<<1, 256, 0, stream>>>((const u16*)w_hh_l0f, dt);
  k_quant<<<256, 256, 0, stream>>>(w_hh_l0f, wq8 + 0 * 65536, dt);
  k_quant<<<256, 256, 0, stream>>>(w_hh_l0b, wq8 + 1 * 65536, dt);
  k_quant<<<256, 256, 0, stream>>>(w_hh_l1f, wq8 + 2 * 65536, dt);
  k_quant<<<256, 256, 0, stream>>>(w_hh_l1b, wq8 + 3 * 65536, dt);
  k_conv_pairs<<<128, 256, 0, stream>>>(w_ih_l0f, wih0 + 0, 32768, dt);
  k_conv_pairs<<<128, 256, 0, stream>>>(w_ih_l0b, wih0 + 32768, 32768, dt);
  k_conv_pairs<<<1024, 256, 0, stream>>>(w_ih_l1f, wih1 + 0, 262144, dt);
  k_conv_pairs<<<1024, 256, 0, stream>>>(w_ih_l1b, wih1 + 262144, 262144, dt);
  k_conv_misc<<<273, 256, 0, stream>>>(b_ih_l0f, b_hh_l0f, b_ih_l0b, b_hh_l0b,
                                       b_ih_l1f, b_hh_l1f, b_ih_l1b, b_hh_l1b,
                                       fcbf, bias, fcw, flags, map, dt);
  k_conv_x<<<4096, 256, 0, stream>>>(Y, dT, xq, dt);
  k_map_set<<<4, 256, 0, stream>>>(idx, map);

  dim3 ggrid(T_SEQ / 64, 16);
  if (par) {
    k_gemm<<<ggrid, 256, 0, stream>>>(xq, wih0, bias, xg, 32);
    k_gemm<<<ggrid, 256, 0, stream>>>(xq, wih0 + 32768, bias + 1024, xg1, 32);
    k_recur3<<<2, 256, 0, stream>>>(xg, wq8, h0, nullptr, nullptr, 0);
    k_gemm<<<ggrid, 256, 0, stream>>>((const u32*)h0, wih1, bias + 2048, xg, 256);
    k_gemm<<<ggrid, 256, 0, stream>>>((const u32*)h0, wih1 + 262144, bias + 3072, xg1, 256);
    k_recur3<<<2, 256, 0, stream>>>(xg, wq8 + 2 * 65536, nullptr, h1g, map, 0);
  } else {
    k_gemm<<<ggrid, 256, 0, stream>>>(xq, wih0, bias, xg, 32);
    k_recur3<<<1, 256, 0, stream>>>(xg, wq8, h0, nullptr, nullptr, 0);
    k_gemm<<<ggrid, 256, 0, stream>>>(xq, wih0 + 32768, bias + 1024, xg, 32);
    k_recur3<<<1, 256, 0, stream>>>(xg, wq8, h0, nullptr, nullptr, 1);
    k_gemm<<<ggrid, 256, 0, stream>>>((const u32*)h0, wih1, bias + 2048, xg, 256);
    k_recur3<<<1, 256, 0, stream>>>(xg, wq8 + 2 * 65536, nullptr, h1g, map, 0);
    k_gemm<<<ggrid, 256, 0, stream>>>((const u32*)h0, wih1 + 262144, bias + 3072, xg, 256);
    k_recur3<<<1, 256, 0, stream>>>(xg, wq8 + 2 * 65536, nullptr, h1g, map, 1);
  }
  k_fc<<<1024, 64, 0, stream>>>(h1g, map, idx, fcw, d_out, dt);
}